// Round 4
// baseline (362.251 us; speedup 1.0000x reference)
//
#include <hip/hip_runtime.h>
#include <math.h>
#include <stdint.h>

#define B_  32
#define T_  4096
#define D_  512
#define V_  32000
#define KW  128   // 0.9^128 = 1.4e-6 -> truncation error ~2e-5 at output, << 6.7e-3

// ===== ROUND-4 DIAGNOSTIC PROBE =====
// k_hidden runs its K-loop REP_HID times, k_head runs its stream REP_HEAD
// times (opaque zero offsets defeat CSE), accumulators rescaled by exact
// 1/2^n. Purpose: per-kernel duration decomposition + get amplified kernels
// into rocprof top-5 (harness fills at ~40us mask everything below).
// REVERT REP_* TO 1 after reading the decomposition.
#define REP_HID  32
#define REP_HEAD 16

typedef __attribute__((ext_vector_type(8))) short bf16x8_t;   // MFMA A/B frag (4 VGPRs)
typedef __attribute__((ext_vector_type(4))) float f32x4_t;    // MFMA C/D frag

// fp32 -> bf16 round-to-nearest-even
__device__ inline unsigned short f2bf(float f) {
    union { float f; uint32_t u; } c; c.f = f;
    return (unsigned short)((c.u + 0x7FFFu + ((c.u >> 16) & 1u)) >> 16);
}

__device__ inline uint4 cvt8(const float4 a, const float4 b) {
    union { unsigned short s[8]; uint4 v; } o;
    o.s[0] = f2bf(a.x); o.s[1] = f2bf(a.y); o.s[2] = f2bf(a.z); o.s[3] = f2bf(a.w);
    o.s[4] = f2bf(b.x); o.s[5] = f2bf(b.y); o.s[6] = f2bf(b.z); o.s[7] = f2bf(b.w);
    return o.v;
}

// -----------------------------------------------------------------------------
// k_prep: unchanged, verified. (blocks 0..127) Ww->bf16 + zero hbuf;
// (blocks 128..1151) gather last-128 window rows -> Abf bf16.
// -----------------------------------------------------------------------------
__global__ __launch_bounds__(256) void k_prep(const int* __restrict__ x,
                                              const float* __restrict__ emb,
                                              const float* __restrict__ Ww,
                                              unsigned short* __restrict__ Wbf,
                                              unsigned short* __restrict__ Abf,
                                              float* __restrict__ hbuf) {
    const int tid = threadIdx.x;
    if (blockIdx.x < 128) {
        const int gid = blockIdx.x * 256 + tid;      // 0..32767
        const int idx = gid * 8;
        const float4 a = *(const float4*)&Ww[idx];
        const float4 b = *(const float4*)&Ww[idx + 4];
        *(uint4*)&Wbf[idx] = cvt8(a, b);
        if (gid < B_ * D_) hbuf[gid] = 0.f;
    } else {
        const int j = (blockIdx.x - 128) * 256 + tid;  // 0..262143 octet-chunks
        const int r = j >> 6;                           // window row 0..4095
        const int c = (j & 63) * 8;                     // k offset
        const int b = r >> 7;
        const int row = x[b * T_ + (T_ - KW) + (r & 127)];
        const float* src = emb + (size_t)row * D_ + c;
        const float4 a = *(const float4*)src;
        const float4 bb = *(const float4*)(src + 4);
        *(uint4*)&Abf[(size_t)r * D_ + c] = cvt8(a, bb);
    }
}

// -----------------------------------------------------------------------------
// k_hidden: PROBE = x32 repetition of the K-loop, acc rescaled by 1/32 (exact).
// Opaque zg (global addr) / zl (LDS index) prevent load CSE / frag hoisting.
// -----------------------------------------------------------------------------
__global__ __launch_bounds__(256) void k_hidden(const unsigned short* __restrict__ Abf,
                                                const unsigned short* __restrict__ Wbf,
                                                const float* __restrict__ Wb,
                                                float* __restrict__ h) {
    __shared__ __align__(16) unsigned short As[512 * 8];   // 512 cells x 16B = 8 KB
    __shared__ __align__(16) unsigned short Bs[1024 * 8];  // 1024 cells = 16 KB
    __shared__ float red[8][64];                           // 2 KB

    const int tid = threadIdx.x;
    const int b   = blockIdx.x >> 5;
    const int e0  = ((blockIdx.x >> 2) & 7) * 64;
    const int ts  = blockIdx.x & 3;

    const int lane = tid & 63;
    const int w    = tid >> 6;
    const int m15  = lane & 15;
    const int q    = lane >> 4;
    const int mt   = w & 1;    // M-tile (16 of 32 rows)
    const int nh   = w >> 1;   // N-half (32 of 64 cols)

    f32x4_t acc[2];
    acc[0] = (f32x4_t){0.f, 0.f, 0.f, 0.f};
    acc[1] = (f32x4_t){0.f, 0.f, 0.f, 0.f};

    const size_t abase = (size_t)(b * KW + ts * 32) * D_;

    int zg = 0, zl = 0;   // opaque zeros (probe)
#pragma unroll 1
    for (int rep = 0; rep < REP_HID; rep++) {
        asm volatile("" : "+v"(zg), "+v"(zl));
        for (int k0 = 0; k0 < D_; k0 += 128) {
            __syncthreads();  // prior phase's frag reads complete before overwrite
            // stage A: 32 rows x 128 k bf16 = 512 cells, 2 per thread
#pragma unroll
            for (int i = 0; i < 2; i++) {
                const int j  = tid + 256 * i;           // cell index
                const int m  = j >> 4;
                const int ko = (j & 15) ^ (m & 15);     // XOR de-swizzle source
                const unsigned short* src = Abf + abase + (size_t)m * D_ + k0 + ko * 8 + zg;
                __builtin_amdgcn_global_load_lds(
                    (const __attribute__((address_space(1))) void*)src,
                    (__attribute__((address_space(3))) void*)&As[j * 8], 16, 0, 0);
            }
            // stage B: 64 rows x 128 k = 1024 cells, 4 per thread
#pragma unroll
            for (int i = 0; i < 4; i++) {
                const int j  = tid + 256 * i;
                const int n  = j >> 4;
                const int ko = (j & 15) ^ (n & 15);
                const unsigned short* src = Wbf + (size_t)(e0 + n) * D_ + k0 + ko * 8 + zg;
                __builtin_amdgcn_global_load_lds(
                    (const __attribute__((address_space(1))) void*)src,
                    (__attribute__((address_space(3))) void*)&Bs[j * 8], 16, 0, 0);
            }
            __syncthreads();

#pragma unroll
            for (int kk = 0; kk < 4; kk++) {
                const int ko = kk * 4 + q;
                const int mA = mt * 16 + m15;
                const int n0 = nh * 32 + m15;
                const int n1 = n0 + 16;
                const bf16x8_t af  = *(const bf16x8_t*)&As[(mA * 16 + (ko ^ m15)) * 8 + zl];
                const bf16x8_t bf0 = *(const bf16x8_t*)&Bs[(n0 * 16 + (ko ^ m15)) * 8 + zl];
                const bf16x8_t bf1 = *(const bf16x8_t*)&Bs[(n1 * 16 + (ko ^ m15)) * 8 + zl];
                acc[0] = __builtin_amdgcn_mfma_f32_16x16x32_bf16(af, bf0, acc[0], 0, 0, 0);
                acc[1] = __builtin_amdgcn_mfma_f32_16x16x32_bf16(af, bf1, acc[1], 0, 0, 0);
            }
        }
    }

    // epilogue: rescale (exact 1/32) + tanh + geometric weight
    float p[2] = {0.f, 0.f};
#pragma unroll
    for (int ni = 0; ni < 2; ni++) {
        const float wbv = Wb[e0 + nh * 32 + ni * 16 + m15];
#pragma unroll
        for (int r = 0; r < 4; r++) {
            const int twin = ts * 32 + mt * 16 + q * 4 + r;
            const float pre = acc[ni][r] * (1.f / REP_HID) + wbv;
            const float e2  = __expf(2.f * pre);
            const float u   = (e2 - 1.f) / (e2 + 1.f);
            const float wt  = 0.1f * exp2f((float)(127 - twin) * -0.15200309344504995f);
            p[ni] += wt * u;
        }
    }
#pragma unroll
    for (int ni = 0; ni < 2; ni++)
        red[mt * 4 + q][nh * 32 + ni * 16 + m15] = p[ni];
    __syncthreads();
    if (tid < 64) {
        float s = 0.f;
#pragma unroll
        for (int g = 0; g < 8; g++) s += red[g][tid];
        atomicAdd(&h[b * D_ + e0 + tid], s);
    }
}

// -----------------------------------------------------------------------------
// k_head: PROBE = x16 repetition of the head_w stream, acc rescaled by 1/16.
// Structure otherwise identical to round-3 verified version (512 thr,
// split-K x4, depth-2 rotated prefetch, padded split-K exchange).
// -----------------------------------------------------------------------------
__global__ __launch_bounds__(512, 6) void k_head(const float* __restrict__ h,
                                                 const float* __restrict__ Whead,
                                                 const float* __restrict__ bhead,
                                                 float* __restrict__ out) {
    __shared__ __align__(16) unsigned short Hs[32 * 520 + 16];  // ~33 KB

    const int tid = threadIdx.x;
    // stage h -> bf16 LDS (512 threads x 4 iters x 8 floats = 16384)
#pragma unroll
    for (int i = 0; i < 4; i++) {
        const int g = (tid + 512 * i) * 8;   // flat float index
        const int r = g >> 9;
        const int c = g & 511;
        const float4 a = *(const float4*)&h[g];
        const float4 b = *(const float4*)&h[g + 4];
        *(uint4*)&Hs[r * 520 + c] = cvt8(a, b);
    }
    __syncthreads();

    const int lane = tid & 63;
    const int w    = tid >> 6;   // 0..7
    const int vt   = w & 1;      // v-tile (16 rows) within block
    const int kh   = w >> 1;     // K-quarter (128 floats)
    const int n    = lane & 15;
    const int q    = lane >> 4;
    const int v    = blockIdx.x * 32 + vt * 16 + n;

    const float* __restrict__ wp = Whead + (size_t)v * D_ + kh * 128 + q * 8;

    f32x4_t acc0 = (f32x4_t){0.f, 0.f, 0.f, 0.f};
    f32x4_t acc1 = (f32x4_t){0.f, 0.f, 0.f, 0.f};

    int zg = 0, zl = 0;   // opaque zeros (probe)
#pragma unroll 1
    for (int rep = 0; rep < REP_HEAD; rep++) {
        asm volatile("" : "+v"(zg), "+v"(zl));
        const float* wr = wp + zg;
        // depth-2 rotated prefetch over 4 ksteps (32B contiguous per thread/kstep)
        float4 pa[3], pb[3];
        pa[0] = *(const float4*)&wr[0];   pb[0] = *(const float4*)&wr[4];
        pa[1] = *(const float4*)&wr[32];  pb[1] = *(const float4*)&wr[36];
#pragma unroll
        for (int ks = 0; ks < 4; ks++) {
            if (ks < 2) {   // constant after unroll -> no dynamic indexing
                pa[(ks + 2) % 3] = *(const float4*)&wr[(ks + 2) * 32];
                pb[(ks + 2) % 3] = *(const float4*)&wr[(ks + 2) * 32 + 4];
            }
            union { uint4 u; bf16x8_t v8; } bfv;
            bfv.u = cvt8(pa[ks % 3], pb[ks % 3]);
            const int kb = kh * 128 + ks * 32 + q * 8 + zl;   // col offset in shorts
            const bf16x8_t a0 = *(const bf16x8_t*)&Hs[n * 520 + kb];
            const bf16x8_t a1 = *(const bf16x8_t*)&Hs[(n + 16) * 520 + kb];
            acc0 = __builtin_amdgcn_mfma_f32_16x16x32_bf16(a0, bfv.v8, acc0, 0, 0, 0);
            acc1 = __builtin_amdgcn_mfma_f32_16x16x32_bf16(a1, bfv.v8, acc1, 0, 0, 0);
        }
    }
    // exact rescale (1/16)
#pragma unroll
    for (int r = 0; r < 4; r++) { acc0[r] *= (1.f / REP_HEAD); acc1[r] *= (1.f / REP_HEAD); }

    // split-K x4 reduction through padded LDS scratch (reuse Hs).
    __syncthreads();   // all h-LDS reads done; safe to reuse as fp32 scratch
    float* Rs = (float*)Hs;
    if (kh > 0) {
        // slot stride 9 floats: lane*9 mod 32 banks -> conflict-free
        float* p = &Rs[((kh - 1) * 128 + vt * 64 + lane) * 9];
#pragma unroll
        for (int r = 0; r < 4; r++) { p[r] = acc0[r]; p[4 + r] = acc1[r]; }
    }
    __syncthreads();
    if (kh == 0) {
        const float bb = bhead[v];
        float s0[4], s1[4];
#pragma unroll
        for (int r = 0; r < 4; r++) { s0[r] = acc0[r] + bb; s1[r] = acc1[r] + bb; }
#pragma unroll
        for (int k = 0; k < 3; k++) {
            const float* p = &Rs[(k * 128 + vt * 64 + lane) * 9];
#pragma unroll
            for (int r = 0; r < 4; r++) { s0[r] += p[r]; s1[r] += p[4 + r]; }
        }
#pragma unroll
        for (int r = 0; r < 4; r++) {
            out[(size_t)(q * 4 + r) * V_ + v]      = s0[r];
            out[(size_t)(16 + q * 4 + r) * V_ + v] = s1[r];
        }
    }
}

extern "C" void kernel_launch(void* const* d_in, const int* in_sizes, int n_in,
                              void* d_out, int out_size, void* d_ws, size_t ws_size,
                              hipStream_t stream) {
    const int*   x      = (const int*)d_in[0];
    const float* emb    = (const float*)d_in[1];
    const float* W_w    = (const float*)d_in[2];
    const float* W_b    = (const float*)d_in[3];
    const float* head_w = (const float*)d_in[4];
    const float* head_b = (const float*)d_in[5];
    float* out = (float*)d_out;

    unsigned short* Wbf  = (unsigned short*)d_ws;                         // 512 KB
    float*          hbuf = (float*)((char*)d_ws + 512 * 1024);            // 64 KB
    unsigned short* Abf  = (unsigned short*)((char*)d_ws + 576 * 1024);   // 4 MB

    k_prep  <<<dim3(1152), dim3(256), 0, stream>>>(x, emb, W_w, Wbf, Abf, hbuf);
    k_hidden<<<dim3(1024), dim3(256), 0, stream>>>(Abf, Wbf, W_b, hbuf);
    k_head  <<<dim3(1000), dim3(512), 0, stream>>>(hbuf, head_w, head_b, out);
}

// Round 5
// 148.403 us; speedup vs baseline: 2.4410x; 2.4410x over previous
//
#include <hip/hip_runtime.h>
#include <math.h>
#include <stdint.h>

#define B_  32
#define T_  4096
#define D_  512
#define V_  32000
#define KW  128   // 0.9^128 = 1.4e-6 -> truncation error ~2e-5 at output, << 6.7e-3

typedef __attribute__((ext_vector_type(8))) short bf16x8_t;   // MFMA A/B frag (4 VGPRs)
typedef __attribute__((ext_vector_type(4))) float f32x4_t;    // MFMA C/D frag

// fp32 -> bf16 round-to-nearest-even
__device__ inline unsigned short f2bf(float f) {
    union { float f; uint32_t u; } c; c.f = f;
    return (unsigned short)((c.u + 0x7FFFu + ((c.u >> 16) & 1u)) >> 16);
}

__device__ inline uint4 cvt8(const float4 a, const float4 b) {
    union { unsigned short s[8]; uint4 v; } o;
    o.s[0] = f2bf(a.x); o.s[1] = f2bf(a.y); o.s[2] = f2bf(a.z); o.s[3] = f2bf(a.w);
    o.s[4] = f2bf(b.x); o.s[5] = f2bf(b.y); o.s[6] = f2bf(b.z); o.s[7] = f2bf(b.w);
    return o.v;
}

// -----------------------------------------------------------------------------
// Decomposition (R4 probe): t_prep ~4us, t_hidden ~2.9us, t_head ~10-12us
// (HBM floor for its 65.5 MB head_w stream); remaining ~130us of the measured
// window is harness poison-fills (3 x 256MiB @ ~40us) + launch gaps — fixed.
// Kernels below are the verified R3 set (149.1us end-to-end).
// -----------------------------------------------------------------------------

// -----------------------------------------------------------------------------
// k_prep: (blocks 0..127)   Ww fp32 -> Wbf bf16 [512][512], zero hbuf
//         (blocks 128..1151) gather last-128 window rows: Abf[4096][512] bf16,
//                            Abf[b*128 + t] = bf16(emb[x[b, T-128+t]])
// All conversions leave the GEMM K-loops entirely.  [verified]
// -----------------------------------------------------------------------------
__global__ __launch_bounds__(256) void k_prep(const int* __restrict__ x,
                                              const float* __restrict__ emb,
                                              const float* __restrict__ Ww,
                                              unsigned short* __restrict__ Wbf,
                                              unsigned short* __restrict__ Abf,
                                              float* __restrict__ hbuf) {
    const int tid = threadIdx.x;
    if (blockIdx.x < 128) {
        const int gid = blockIdx.x * 256 + tid;      // 0..32767
        const int idx = gid * 8;
        const float4 a = *(const float4*)&Ww[idx];
        const float4 b = *(const float4*)&Ww[idx + 4];
        *(uint4*)&Wbf[idx] = cvt8(a, b);
        if (gid < B_ * D_) hbuf[gid] = 0.f;
    } else {
        const int j = (blockIdx.x - 128) * 256 + tid;  // 0..262143 octet-chunks
        const int r = j >> 6;                           // window row 0..4095
        const int c = (j & 63) * 8;                     // k offset
        const int b = r >> 7;
        const int row = x[b * T_ + (T_ - KW) + (r & 127)];
        const float* src = emb + (size_t)row * D_ + c;
        const float4 a = *(const float4*)src;
        const float4 bb = *(const float4*)(src + 4);
        *(uint4*)&Abf[(size_t)r * D_ + c] = cvt8(a, bb);
    }
}

// -----------------------------------------------------------------------------
// k_hidden: partial h[b][e] over a 32-row window slice, bf16 MFMA.  [verified]
// Grid 1024 = b(32) x e-chunk(8, 64 wide) x t-slice(4, 32 rows) -> 4 blocks/CU.
// -----------------------------------------------------------------------------
__global__ __launch_bounds__(256) void k_hidden(const unsigned short* __restrict__ Abf,
                                                const unsigned short* __restrict__ Wbf,
                                                const float* __restrict__ Wb,
                                                float* __restrict__ h) {
    __shared__ __align__(16) unsigned short As[512 * 8];   // 512 cells x 16B = 8 KB
    __shared__ __align__(16) unsigned short Bs[1024 * 8];  // 1024 cells = 16 KB
    __shared__ float red[8][64];                           // 2 KB

    const int tid = threadIdx.x;
    const int b   = blockIdx.x >> 5;
    const int e0  = ((blockIdx.x >> 2) & 7) * 64;
    const int ts  = blockIdx.x & 3;

    const int lane = tid & 63;
    const int w    = tid >> 6;
    const int m15  = lane & 15;
    const int q    = lane >> 4;
    const int mt   = w & 1;    // M-tile (16 of 32 rows)
    const int nh   = w >> 1;   // N-half (32 of 64 cols)

    f32x4_t acc[2];
    acc[0] = (f32x4_t){0.f, 0.f, 0.f, 0.f};
    acc[1] = (f32x4_t){0.f, 0.f, 0.f, 0.f};

    const size_t abase = (size_t)(b * KW + ts * 32) * D_;

    for (int k0 = 0; k0 < D_; k0 += 128) {
        __syncthreads();  // prior phase's frag reads complete before overwrite
        // stage A: 32 rows x 128 k bf16 = 512 cells, 2 per thread
#pragma unroll
        for (int i = 0; i < 2; i++) {
            const int j  = tid + 256 * i;           // cell index
            const int m  = j >> 4;
            const int ko = (j & 15) ^ (m & 15);     // XOR de-swizzle source
            const unsigned short* src = Abf + abase + (size_t)m * D_ + k0 + ko * 8;
            __builtin_amdgcn_global_load_lds(
                (const __attribute__((address_space(1))) void*)src,
                (__attribute__((address_space(3))) void*)&As[j * 8], 16, 0, 0);
        }
        // stage B: 64 rows x 128 k = 1024 cells, 4 per thread
#pragma unroll
        for (int i = 0; i < 4; i++) {
            const int j  = tid + 256 * i;
            const int n  = j >> 4;
            const int ko = (j & 15) ^ (n & 15);
            const unsigned short* src = Wbf + (size_t)(e0 + n) * D_ + k0 + ko * 8;
            __builtin_amdgcn_global_load_lds(
                (const __attribute__((address_space(1))) void*)src,
                (__attribute__((address_space(3))) void*)&Bs[j * 8], 16, 0, 0);
        }
        __syncthreads();

#pragma unroll
        for (int kk = 0; kk < 4; kk++) {
            const int ko = kk * 4 + q;
            const int mA = mt * 16 + m15;
            const int n0 = nh * 32 + m15;
            const int n1 = n0 + 16;
            const bf16x8_t af  = *(const bf16x8_t*)&As[(mA * 16 + (ko ^ m15)) * 8];
            const bf16x8_t bf0 = *(const bf16x8_t*)&Bs[(n0 * 16 + (ko ^ m15)) * 8];
            const bf16x8_t bf1 = *(const bf16x8_t*)&Bs[(n1 * 16 + (ko ^ m15)) * 8];
            acc[0] = __builtin_amdgcn_mfma_f32_16x16x32_bf16(af, bf0, acc[0], 0, 0, 0);
            acc[1] = __builtin_amdgcn_mfma_f32_16x16x32_bf16(af, bf1, acc[1], 0, 0, 0);
        }
    }

    // epilogue: tanh + geometric weight; C/D: row(M)=q*4+r, col(N)=m15
    float p[2] = {0.f, 0.f};
#pragma unroll
    for (int ni = 0; ni < 2; ni++) {
        const float wbv = Wb[e0 + nh * 32 + ni * 16 + m15];
#pragma unroll
        for (int r = 0; r < 4; r++) {
            const int twin = ts * 32 + mt * 16 + q * 4 + r;
            const float pre = acc[ni][r] + wbv;
            const float e2  = __expf(2.f * pre);
            const float u   = (e2 - 1.f) / (e2 + 1.f);
            const float wt  = 0.1f * exp2f((float)(127 - twin) * -0.15200309344504995f);
            p[ni] += wt * u;
        }
    }
#pragma unroll
    for (int ni = 0; ni < 2; ni++)
        red[mt * 4 + q][nh * 32 + ni * 16 + m15] = p[ni];
    __syncthreads();
    if (tid < 64) {
        float s = 0.f;
#pragma unroll
        for (int g = 0; g < 8; g++) s += red[g][tid];
        atomicAdd(&h[b * D_ + e0 + tid], s);
    }
}

// -----------------------------------------------------------------------------
// k_head: out[32][32000] = h @ head_w^T + head_b, plain-bf16 MFMA.  [verified]
// 512-thread blocks, grid 1000, split-K x4 across waves, depth-2 rotated
// prefetch, 3 blocks/CU. Runs at the HBM floor for its 65.5 MB stream.
// -----------------------------------------------------------------------------
__global__ __launch_bounds__(512, 6) void k_head(const float* __restrict__ h,
                                                 const float* __restrict__ Whead,
                                                 const float* __restrict__ bhead,
                                                 float* __restrict__ out) {
    __shared__ __align__(16) unsigned short Hs[32 * 520 + 16];  // ~33 KB

    const int tid = threadIdx.x;
    // stage h -> bf16 LDS (512 threads x 4 iters x 8 floats = 16384)
#pragma unroll
    for (int i = 0; i < 4; i++) {
        const int g = (tid + 512 * i) * 8;   // flat float index
        const int r = g >> 9;
        const int c = g & 511;
        const float4 a = *(const float4*)&h[g];
        const float4 b = *(const float4*)&h[g + 4];
        *(uint4*)&Hs[r * 520 + c] = cvt8(a, b);
    }
    __syncthreads();

    const int lane = tid & 63;
    const int w    = tid >> 6;   // 0..7
    const int vt   = w & 1;      // v-tile (16 rows) within block
    const int kh   = w >> 1;     // K-quarter (128 floats)
    const int n    = lane & 15;
    const int q    = lane >> 4;
    const int v    = blockIdx.x * 32 + vt * 16 + n;

    const float* __restrict__ wp = Whead + (size_t)v * D_ + kh * 128 + q * 8;

    f32x4_t acc0 = (f32x4_t){0.f, 0.f, 0.f, 0.f};
    f32x4_t acc1 = (f32x4_t){0.f, 0.f, 0.f, 0.f};

    // depth-2 rotated prefetch over 4 ksteps (32B contiguous per thread/kstep)
    float4 pa[3], pb[3];
    pa[0] = *(const float4*)&wp[0];   pb[0] = *(const float4*)&wp[4];
    pa[1] = *(const float4*)&wp[32];  pb[1] = *(const float4*)&wp[36];
#pragma unroll
    for (int ks = 0; ks < 4; ks++) {
        if (ks < 2) {   // constant after unroll -> no dynamic indexing (rule #20)
            pa[(ks + 2) % 3] = *(const float4*)&wp[(ks + 2) * 32];
            pb[(ks + 2) % 3] = *(const float4*)&wp[(ks + 2) * 32 + 4];
        }
        union { uint4 u; bf16x8_t v8; } bfv;
        bfv.u = cvt8(pa[ks % 3], pb[ks % 3]);
        const int kb = kh * 128 + ks * 32 + q * 8;   // col offset in shorts
        const bf16x8_t a0 = *(const bf16x8_t*)&Hs[n * 520 + kb];
        const bf16x8_t a1 = *(const bf16x8_t*)&Hs[(n + 16) * 520 + kb];
        acc0 = __builtin_amdgcn_mfma_f32_16x16x32_bf16(a0, bfv.v8, acc0, 0, 0, 0);
        acc1 = __builtin_amdgcn_mfma_f32_16x16x32_bf16(a1, bfv.v8, acc1, 0, 0, 0);
    }

    // split-K x4 reduction through padded LDS scratch (reuse Hs).
    __syncthreads();   // all h-LDS reads done; safe to reuse as fp32 scratch
    float* Rs = (float*)Hs;
    if (kh > 0) {
        // slot stride 9 floats: lane*9 mod 32 banks -> conflict-free
        float* p = &Rs[((kh - 1) * 128 + vt * 64 + lane) * 9];
#pragma unroll
        for (int r = 0; r < 4; r++) { p[r] = acc0[r]; p[4 + r] = acc1[r]; }
    }
    __syncthreads();
    if (kh == 0) {
        const float bb = bhead[v];
        float s0[4], s1[4];
#pragma unroll
        for (int r = 0; r < 4; r++) { s0[r] = acc0[r] + bb; s1[r] = acc1[r] + bb; }
#pragma unroll
        for (int k = 0; k < 3; k++) {
            const float* p = &Rs[(k * 128 + vt * 64 + lane) * 9];
#pragma unroll
            for (int r = 0; r < 4; r++) { s0[r] += p[r]; s1[r] += p[4 + r]; }
        }
#pragma unroll
        for (int r = 0; r < 4; r++) {
            out[(size_t)(q * 4 + r) * V_ + v]      = s0[r];
            out[(size_t)(16 + q * 4 + r) * V_ + v] = s1[r];
        }
    }
}

extern "C" void kernel_launch(void* const* d_in, const int* in_sizes, int n_in,
                              void* d_out, int out_size, void* d_ws, size_t ws_size,
                              hipStream_t stream) {
    const int*   x      = (const int*)d_in[0];
    const float* emb    = (const float*)d_in[1];
    const float* W_w    = (const float*)d_in[2];
    const float* W_b    = (const float*)d_in[3];
    const float* head_w = (const float*)d_in[4];
    const float* head_b = (const float*)d_in[5];
    float* out = (float*)d_out;

    unsigned short* Wbf  = (unsigned short*)d_ws;                         // 512 KB
    float*          hbuf = (float*)((char*)d_ws + 512 * 1024);            // 64 KB
    unsigned short* Abf  = (unsigned short*)((char*)d_ws + 576 * 1024);   // 4 MB

    k_prep  <<<dim3(1152), dim3(256), 0, stream>>>(x, emb, W_w, Wbf, Abf, hbuf);
    k_hidden<<<dim3(1024), dim3(256), 0, stream>>>(Abf, Wbf, W_b, hbuf);
    k_head  <<<dim3(1000), dim3(512), 0, stream>>>(hbuf, head_w, head_b, out);
}